// Round 8
// baseline (192.518 us; speedup 1.0000x reference)
//
#include <hip/hip_runtime.h>
#include <math.h>

// Shapes fixed by setup_inputs(): B=8, N=8192, M=512 clusters, S=64 samples.
#define BB 8
#define NN 8192
#define MM 512
#define SS 64
#define NCLUST (BB*MM)                 // 4096

// d_out layout (flat, return order, all read back as f32):
// new_xyz[8*512*3] | idx(as float)[8*512*64] | attention[8*512] | orientation[8*512]
#define OUT_IDX   (BB*MM*3)            // 12288
#define OUT_ATT   (OUT_IDX + BB*MM*SS) // 274432
#define OUT_ORI   (OUT_ATT + BB*MM)    // 278528

// d_ws layout (ushort units):
// [0,8192)            W2 B-frags (bf16)
// [8192,40960)        W3 B-frags (bf16)
// [40960,1089536)     pooled v (bf16)  4096*256
// [1089536,...)       g (f32) 4096*64*4 floats = 4 MB (16B-aligned)
#define WS_W3 8192
#define WS_V  40960
#define WS_G  1089536

typedef short v8s __attribute__((ext_vector_type(8)));   // 8 bf16 (MFMA A/B frag)
typedef float v4f __attribute__((ext_vector_type(4)));   // MFMA C/D frag

static __device__ __forceinline__ unsigned short f2bf(float x) {
    unsigned int u = __float_as_uint(x);
    u += 0x7FFFu + ((u >> 16) & 1u);     // round-to-nearest-even
    return (unsigned short)(u >> 16);
}

// ---- Kernel 0: pack W2 (64x128) and W3 (128x256) fp32 -> bf16 MFMA B-frag
// layout. B-frag lane l holds B[kt*32+(l>>4)*8+j][nt*16+(l&15)], j=0..7,
// stored contiguous (16 B/lane) so the MLP kernel loads one dwordx4/frag.
__global__ void pack_weights(const float* __restrict__ W2,
                             const float* __restrict__ W3,
                             unsigned short* __restrict__ ws)
{
    const int gid = blockIdx.x * 256 + threadIdx.x;    // 0..5119
    const float* W; unsigned short* dst; int N, kt, nt, lane;
    if (gid < 1024) {                   // W2: 16 tiles * 64 lanes
        W = W2; N = 128;
        const int tile = gid >> 6; lane = gid & 63;
        kt = tile >> 3; nt = tile & 7;
        dst = ws + (size_t)(tile * 64 + lane) * 8;
    } else {                            // W3: 64 tiles * 64 lanes
        const int g = gid - 1024;
        W = W3; N = 256;
        const int tile = g >> 6; lane = g & 63;
        kt = tile >> 4; nt = tile & 15;
        dst = ws + WS_W3 + (size_t)(tile * 64 + lane) * 8;
    }
    const int k0 = kt * 32 + (lane >> 4) * 8;
    const int n  = nt * 16 + (lane & 15);
    union { unsigned short u[8]; v8s v; } f;
    #pragma unroll
    for (int j = 0; j < 8; ++j) f.u[j] = f2bf(W[(k0 + j) * N + n]);
    *(v8s*)dst = f.v;
}

// ---- Kernel 1: ball query, ONE WAVE PER CLUSTER. Zero barriers, no LDS,
// low regs -> 16 waves/CU resident: the serial scan latency is hidden by TLP.
// First 64 indices with d2 < 4.0 in index order; pads use the first valid
// neighbor (tracked in registers via shfl; nonempty since center is its own
// neighbor). Writes g rows (f32, exact) to ws and idx/new_xyz to out. ----
__global__ __launch_bounds__(256, 8) void feat3d_bq(
    const float* __restrict__ xyz,
    float* __restrict__ gws,
    float* __restrict__ out)
{
    const int t  = threadIdx.x;
    const int l  = t & 63;
    const int cg = blockIdx.x * 4 + (t >> 6);   // this wave's cluster
    const int b  = cg >> 9;
    const int m  = cg & 511;
    const float* xb = xyz + (size_t)b * (NN * 3);

    const float cx = xb[m*3+0], cy = xb[m*3+1], cz = xb[m*3+2];
    if (l < 3) out[cg*3 + l] = xb[m*3 + l];     // new_xyz

    float4* gdst = (float4*)(gws + (size_t)cg * 256);
    float*  idst = out + OUT_IDX + (size_t)cg * SS;

    int cnt = 0, base = 0, fIdx = -1;
    float fx = 0.f, fy = 0.f, fz = 0.f;
    while (base < NN && cnt < SS) {
        const int j = base + l;
        const float dx = xb[j*3+0] - cx;
        const float dy = xb[j*3+1] - cy;
        const float dz = xb[j*3+2] - cz;
        // no fma contraction: idx must be exact at the d2==4.0 boundary
        const float d2 = __fadd_rn(__fadd_rn(__fmul_rn(dx,dx), __fmul_rn(dy,dy)),
                                   __fmul_rn(dz,dz));
        const bool valid = d2 < 4.0f;
        const unsigned long long mask = __ballot(valid);   // wave-wide (64b)
        const int below = __popcll(mask & ((1ull << l) - 1ull));
        const int pos = cnt + below;
        if (valid && pos < SS) {
            gdst[pos] = make_float4(dx*0.5f, dy*0.5f, dz*0.5f, 0.f);
            idst[pos] = (float)j;               // idx stored as float
        }
        if (fIdx < 0 && mask != 0ull) {         // first valid (uniform lane id)
            const int fl = (int)__builtin_ctzll(mask);
            fIdx = base + fl;
            fx = __shfl(dx, fl); fy = __shfl(dy, fl); fz = __shfl(dz, fl);
        }
        cnt += (int)__popcll(mask);
        if (cnt > SS) cnt = SS;
        base += 64;
    }
    if (l >= cnt) {                             // cnt<64 => full scan done
        gdst[l] = make_float4(fx*0.5f, fy*0.5f, fz*0.5f, 0.f);
        idst[l] = (float)fIdx;
    }
}

// ---- Kernel 2: MLP front (1 cluster/block, R6's proven tiling, no BQ).
// g read straight from ws (per-lane float4, no staging barrier). 25.6 KB LDS,
// bound (256,5): 68 VGPR + 32 AGPR = 100 <= 102 -> 5 blocks/CU. ----
__global__ __launch_bounds__(256, 5) void feat3d_mlp(
    const float* __restrict__ gws,
    const float* __restrict__ W1, const float* __restrict__ b1,
    const float* __restrict__ b2, const float* __restrict__ b3,
    const unsigned short* __restrict__ Wp,
    unsigned short* __restrict__ vdst)
{
    __shared__ __align__(16) unsigned char lds[25600];
    unsigned short* a2p = (unsigned short*)lds;            // h1 A-frags, 8 KB
    unsigned short* a3p = (unsigned short*)(lds + 8192);   // h2 A-frags, 16 KB
    float* ls_w1        = (float*)(lds + 24576);           // [64][4], 1 KB

    const int t   = threadIdx.x;
    const int wv  = t >> 6;
    const int l   = t & 63;
    const int q   = l >> 4;
    const int r16 = l & 15;
    const int blk = blockIdx.x;                // cluster id

    // Prefetch W2 B-frags (one dwordx4 each) immediately.
    const v8s* W2f = (const v8s*)Wp;
    v8s bfr[2][2];
    #pragma unroll
    for (int kt = 0; kt < 2; ++kt)
        #pragma unroll
        for (int ni = 0; ni < 2; ++ni)
            bfr[kt][ni] = W2f[(kt*8 + 2*wv + ni)*64 + l];

    // This thread's g row (s = wv*16 + r16); quads share the row (L1 bcast).
    const int s = wv*16 + r16;
    const float4 g4 = *(const float4*)(gws + (size_t)blk*256 + s*4);

    // Stage W1^T + b1.
    if (t < 64) {
        ls_w1[t*4+0] = W1[t];
        ls_w1[t*4+1] = W1[64 + t];
        ls_w1[t*4+2] = W1[128 + t];
        ls_w1[t*4+3] = b1[t];
    }
    __syncthreads();

    // ---- L1 (fp32) + pack h1 into A-frag layout: c = kt*32 + q*8 + j ----
    {
        #pragma unroll
        for (int kt = 0; kt < 2; ++kt) {
            union { unsigned short u[8]; v8s v; } fr;
            #pragma unroll
            for (int j = 0; j < 8; ++j) {
                const int c = kt*32 + q*8 + j;
                const float4 w = *(const float4*)&ls_w1[c*4];
                const float h = fmaf(g4.x, w.x, fmaf(g4.y, w.y,
                                fmaf(g4.z, w.z, w.w)));
                fr.u[j] = f2bf(fmaxf(h, 0.f));
            }
            *(v8s*)&a2p[((kt*4 + wv)*64 + l)*8] = fr.v;
        }
    }
    __syncthreads();

    // ---- L2 MFMA: h2 = relu(h1 @ W2 + b2). Wave wv owns nt {2wv, 2wv+1}. ----
    {
        const v4f z = {0.f, 0.f, 0.f, 0.f};
        v4f acc[4][2];
        #pragma unroll
        for (int mt = 0; mt < 4; ++mt) { acc[mt][0] = z; acc[mt][1] = z; }

        #pragma unroll
        for (int kt = 0; kt < 2; ++kt)
            #pragma unroll
            for (int mt = 0; mt < 4; ++mt) {
                const v8s a = *(const v8s*)&a2p[((kt*4 + mt)*64 + l)*8];
                acc[mt][0] = __builtin_amdgcn_mfma_f32_16x16x32_bf16(
                    a, bfr[kt][0], acc[mt][0], 0, 0, 0);
                acc[mt][1] = __builtin_amdgcn_mfma_f32_16x16x32_bf16(
                    a, bfr[kt][1], acc[mt][1], 0, 0, 0);
            }

        // Epilogue: +b2, relu, bf16, scatter into L3 A-frag layout.
        // C/D elem (mt,ni,rg): row s2 = mt*16+q*4+rg, col c2 = (2wv+ni)*16+r16.
        #pragma unroll
        for (int ni = 0; ni < 2; ++ni) {
            const int c2  = (2*wv + ni)*16 + r16;
            const float bias = b2[c2];
            const int kt3 = c2 >> 5;
            const int lhi = ((c2 >> 3) & 3) << 4;
            const int j3  = c2 & 7;
            #pragma unroll
            for (int mt = 0; mt < 4; ++mt)
                #pragma unroll
                for (int rg = 0; rg < 4; ++rg) {
                    const float h = fmaxf(acc[mt][ni][rg] + bias, 0.f);
                    const int s15 = q*4 + rg;
                    a3p[((kt3*4 + mt)*64 + (lhi | s15))*8 + j3] = f2bf(h);
                }
        }
    }
    __syncthreads();

    // ---- L3 MFMA in 2 N-passes (acc[4][2] bounds regs). Wave wv owns
    // nt {4wv..4wv+3}; W3 B-frags pipelined one kt ahead. Pool in regs. ----
    {
        const v8s* W3f = (const v8s*)(Wp + WS_W3);
        unsigned short* vrow = vdst + (size_t)blk * 256;

        #pragma unroll
        for (int np = 0; np < 2; ++np) {
            const int nt0 = 4*wv + 2*np;
            const v4f z = {0.f, 0.f, 0.f, 0.f};
            v4f acc[4][2];
            #pragma unroll
            for (int mt = 0; mt < 4; ++mt) { acc[mt][0] = z; acc[mt][1] = z; }

            v8s bb0 = W3f[(nt0    )*64 + l];        // kt = 0
            v8s bb1 = W3f[(nt0 + 1)*64 + l];
            #pragma unroll
            for (int kt = 0; kt < 4; ++kt) {
                v8s a[4];
                #pragma unroll
                for (int mt = 0; mt < 4; ++mt)
                    a[mt] = *(const v8s*)&a3p[((kt*4 + mt)*64 + l)*8];
                v8s nb0, nb1;
                if (kt < 3) {
                    nb0 = W3f[((kt+1)*16 + nt0    )*64 + l];
                    nb1 = W3f[((kt+1)*16 + nt0 + 1)*64 + l];
                }
                #pragma unroll
                for (int mt = 0; mt < 4; ++mt) {
                    acc[mt][0] = __builtin_amdgcn_mfma_f32_16x16x32_bf16(
                        a[mt], bb0, acc[mt][0], 0, 0, 0);
                    acc[mt][1] = __builtin_amdgcn_mfma_f32_16x16x32_bf16(
                        a[mt], bb1, acc[mt][1], 0, 0, 0);
                }
                if (kt < 3) { bb0 = nb0; bb1 = nb1; }
            }

            // Pool over samples (16 regs + cross-quad shfl); bias+relu after
            // pool (relu monotone, bias per-column => commutes). Store bf16 v.
            #pragma unroll
            for (int ni = 0; ni < 2; ++ni) {
                float mx = acc[0][ni][0];
                #pragma unroll
                for (int mt = 0; mt < 4; ++mt)
                    #pragma unroll
                    for (int rg = 0; rg < 4; ++rg)
                        mx = fmaxf(mx, acc[mt][ni][rg]);
                mx = fmaxf(mx, __shfl_xor(mx, 16));
                mx = fmaxf(mx, __shfl_xor(mx, 32));
                if (q == 0) {
                    const int c = (nt0 + ni)*16 + r16;
                    vrow[c] = f2bf(fmaxf(mx + b3[c], 0.f));
                }
            }
        }
    }
}

// ---- Kernel 3: tail — 16 clusters/block; W4/W5 read 256x fewer times.
// L4/L5 fp32; heads fused. ----
__global__ __launch_bounds__(256) void feat3d_tail(
    const unsigned short* __restrict__ vsrc,
    const float* __restrict__ W4, const float* __restrict__ b4,
    const float* __restrict__ W5, const float* __restrict__ b5,
    const float* __restrict__ Wa, const float* __restrict__ ba,
    const float* __restrict__ Wo, const float* __restrict__ bo,
    float* __restrict__ out)
{
    __shared__ __align__(16) float V[16][256];    // 16 KB
    __shared__ __align__(16) float H4[16][128];   // 8 KB
    __shared__ __align__(16) float H5[16][64];    // 4 KB

    const int t   = threadIdx.x;
    const int cl0 = blockIdx.x * 16;

    // Load V tile (bf16 -> f32), coalesced uint4 (8 shorts each, x2/thread).
    {
        const int i  = t >> 4;
        const int ch = t & 15;
        const uint4* src = (const uint4*)(vsrc + (size_t)(cl0 + i) * 256);
        #pragma unroll
        for (int h = 0; h < 2; ++h) {
            const uint4 r = src[ch*2 + h];
            const unsigned int u[4] = {r.x, r.y, r.z, r.w};
            #pragma unroll
            for (int j = 0; j < 4; ++j) {
                V[i][ch*16 + h*8 + 2*j]     = __uint_as_float(u[j] << 16);
                V[i][ch*16 + h*8 + 2*j + 1] = __uint_as_float(u[j] & 0xFFFF0000u);
            }
        }
    }
    __syncthreads();

    // L4: h4[i][c] = b4[c] + sum_k V[i][k] W4[k][c]; thread = (c, 8 clusters).
    {
        const int c  = t & 127;
        const int ih = t >> 7;
        float acc[8];
        #pragma unroll
        for (int i = 0; i < 8; ++i) acc[i] = b4[c];
        for (int k4 = 0; k4 < 64; ++k4) {
            const float w0 = W4[(4*k4+0)*128 + c];
            const float w1 = W4[(4*k4+1)*128 + c];
            const float w2 = W4[(4*k4+2)*128 + c];
            const float w3 = W4[(4*k4+3)*128 + c];
            #pragma unroll
            for (int i = 0; i < 8; ++i) {
                const float4 vv = *(const float4*)&V[ih*8 + i][4*k4];
                acc[i] = fmaf(vv.x, w0, fmaf(vv.y, w1,
                         fmaf(vv.z, w2, fmaf(vv.w, w3, acc[i]))));
            }
        }
        #pragma unroll
        for (int i = 0; i < 8; ++i) H4[ih*8 + i][c] = acc[i];
    }
    __syncthreads();

    // L5: h5[i][c] = b5[c] + sum_k H4[i][k] W5[k][c]; thread = (c, 4 clusters).
    {
        const int c  = t & 63;
        const int iq = t >> 6;
        float acc[4];
        #pragma unroll
        for (int i = 0; i < 4; ++i) acc[i] = b5[c];
        for (int k4 = 0; k4 < 32; ++k4) {
            const float w0 = W5[(4*k4+0)*64 + c];
            const float w1 = W5[(4*k4+1)*64 + c];
            const float w2 = W5[(4*k4+2)*64 + c];
            const float w3 = W5[(4*k4+3)*64 + c];
            #pragma unroll
            for (int i = 0; i < 4; ++i) {
                const float4 vv = *(const float4*)&H4[iq*4 + i][4*k4];
                acc[i] = fmaf(vv.x, w0, fmaf(vv.y, w1,
                         fmaf(vv.z, w2, fmaf(vv.w, w3, acc[i]))));
            }
        }
        #pragma unroll
        for (int i = 0; i < 4; ++i) H5[iq*4 + i][c] = acc[i];
    }
    __syncthreads();

    // Heads: wave wv handles clusters 4wv..4wv+3. attention = softplus(h5.Wa+ba);
    // orientation = atan2(o1,o0) (normalization is scale-invariant -> skipped).
    {
        const int wv = t >> 6, l = t & 63;
        const float wa  = Wa[l];
        const float wo0 = Wo[2*l + 0];
        const float wo1 = Wo[2*l + 1];
        #pragma unroll
        for (int i = 0; i < 4; ++i) {
            const float hv = H5[4*wv + i][l];
            float va = hv * wa;
            float v0 = hv * wo0;
            float v1 = hv * wo1;
            #pragma unroll
            for (int off = 32; off > 0; off >>= 1) {
                va += __shfl_down(va, off);
                v0 += __shfl_down(v0, off);
                v1 += __shfl_down(v1, off);
            }
            if (l == 0) {
                const int cg = cl0 + 4*wv + i;
                const float a = va + ba[0];
                out[OUT_ATT + cg] = fmaxf(a, 0.f) + log1pf(expf(-fabsf(a)));
                out[OUT_ORI + cg] = atan2f(v1 + bo[1], v0 + bo[0]);
            }
        }
    }
}

extern "C" void kernel_launch(void* const* d_in, const int* in_sizes, int n_in,
                              void* d_out, int out_size, void* d_ws, size_t ws_size,
                              hipStream_t stream) {
    const float* xyz = (const float*)d_in[0];
    const float* W1  = (const float*)d_in[1];
    const float* b1  = (const float*)d_in[2];
    const float* W2  = (const float*)d_in[3];
    const float* b2  = (const float*)d_in[4];
    const float* W3  = (const float*)d_in[5];
    const float* b3  = (const float*)d_in[6];
    const float* W4  = (const float*)d_in[7];
    const float* b4  = (const float*)d_in[8];
    const float* W5  = (const float*)d_in[9];
    const float* b5  = (const float*)d_in[10];
    const float* Wa  = (const float*)d_in[11];
    const float* ba  = (const float*)d_in[12];
    const float* Wo  = (const float*)d_in[13];
    const float* bo  = (const float*)d_in[14];

    unsigned short* ws = (unsigned short*)d_ws;
    float* gws = (float*)(ws + WS_G);

    pack_weights<<<dim3(20), dim3(256), 0, stream>>>(W2, W3, ws);
    feat3d_bq<<<dim3(NCLUST/4), dim3(256), 0, stream>>>(
        xyz, gws, (float*)d_out);
    feat3d_mlp<<<dim3(NCLUST), dim3(256), 0, stream>>>(
        gws, W1, b1, b2, b3, ws, ws + WS_V);
    feat3d_tail<<<dim3(NCLUST/16), dim3(256), 0, stream>>>(
        ws + WS_V, W4, b4, W5, b5, Wa, ba, Wo, bo, (float*)d_out);
}

// Round 9
// 173.888 us; speedup vs baseline: 1.1071x; 1.1071x over previous
//
#include <hip/hip_runtime.h>
#include <math.h>

// Shapes fixed by setup_inputs(): B=8, N=8192, M=512 clusters, S=64 samples.
#define BB 8
#define NN 8192
#define MM 512
#define SS 64
#define NCLUST (BB*MM)                 // 4096

// d_out layout (flat, return order, all read back as f32):
// new_xyz[8*512*3] | idx(as float)[8*512*64] | attention[8*512] | orientation[8*512]
#define OUT_IDX   (BB*MM*3)            // 12288
#define OUT_ATT   (OUT_IDX + BB*MM*SS) // 274432
#define OUT_ORI   (OUT_ATT + BB*MM)    // 278528

// d_ws layout (ushort units unless noted):
// [0,8192)            W2 B-frags (bf16)
// [8192,40960)        W3 B-frags (bf16)
// [40960,1089536)     pooled v (bf16)  4096*256
// byte 2179072:       validity masks, u64[4096][128] = 4 MB
#define WS_W3 8192
#define WS_V  40960
#define WS_MASK_BYTES 2179072

typedef short v8s __attribute__((ext_vector_type(8)));   // 8 bf16 (MFMA A/B frag)
typedef float v4f __attribute__((ext_vector_type(4)));   // MFMA C/D frag

static __device__ __forceinline__ unsigned short f2bf(float x) {
    unsigned int u = __float_as_uint(x);
    u += 0x7FFFu + ((u >> 16) & 1u);     // round-to-nearest-even
    return (unsigned short)(u >> 16);
}

// ---- Kernel 0: pack W2 (64x128) and W3 (128x256) fp32 -> bf16 MFMA B-frag
// layout. B-frag lane l holds B[kt*32+(l>>4)*8+j][nt*16+(l&15)], j=0..7,
// stored contiguous (16 B/lane) so the MLP kernel loads one dwordx4/frag.
__global__ void pack_weights(const float* __restrict__ W2,
                             const float* __restrict__ W3,
                             unsigned short* __restrict__ ws)
{
    const int gid = blockIdx.x * 256 + threadIdx.x;    // 0..5119
    const float* W; unsigned short* dst; int N, kt, nt, lane;
    if (gid < 1024) {                   // W2: 16 tiles * 64 lanes
        W = W2; N = 128;
        const int tile = gid >> 6; lane = gid & 63;
        kt = tile >> 3; nt = tile & 7;
        dst = ws + (size_t)(tile * 64 + lane) * 8;
    } else {                            // W3: 64 tiles * 64 lanes
        const int g = gid - 1024;
        W = W3; N = 256;
        const int tile = g >> 6; lane = g & 63;
        kt = tile >> 4; nt = tile & 15;
        dst = ws + WS_W3 + (size_t)(tile * 64 + lane) * 8;
    }
    const int k0 = kt * 32 + (lane >> 4) * 8;
    const int n  = nt * 16 + (lane & 15);
    union { unsigned short u[8]; v8s v; } f;
    #pragma unroll
    for (int j = 0; j < 8; ++j) f.u[j] = f2bf(W[(k0 + j) * N + n]);
    *(v8s*)dst = f.v;
}

// ---- Kernel 1: validity masks, fully parallel (NO serial scan, NO tail).
// Block = (batch b, 16-cluster group, 256-point chunk). Each thread holds one
// point; 16 ballots -> 64 mask words per block. 8192 blocks, dense VALU.
__global__ __launch_bounds__(256) void feat3d_mask(
    const float* __restrict__ xyz,
    unsigned long long* __restrict__ mask)
{
    const int t    = threadIdx.x;
    const int l    = t & 63;
    const int blk  = blockIdx.x;            // 8 * 32 * 32
    const int b    = blk >> 10;
    const int rem  = blk & 1023;
    const int grp  = rem >> 5;              // 16-cluster group 0..31
    const int chun = rem & 31;              // 256-pt chunk 0..31
    const float* xb = xyz + (size_t)b * (NN * 3);

    const int p = chun * 256 + t;
    const float px = xb[p*3+0], py = xb[p*3+1], pz = xb[p*3+2];
    const int wsub = chun*4 + (t >> 6);     // word index within cluster (p>>6)

    #pragma unroll 4
    for (int i = 0; i < 16; ++i) {
        const int m = grp*16 + i;
        const float cx = xb[m*3+0], cy = xb[m*3+1], cz = xb[m*3+2];
        const float dx = px - cx;
        const float dy = py - cy;
        const float dz = pz - cz;
        // no fma contraction: idx must be exact at the d2==4.0 boundary
        const float d2 = __fadd_rn(__fadd_rn(__fmul_rn(dx,dx), __fmul_rn(dy,dy)),
                                   __fmul_rn(dz,dz));
        const unsigned long long mk = __ballot(d2 < 4.0f);
        if (l == 0)
            mask[(size_t)(b*512 + m) * 128 + wsub] = mk;
    }
}

// ---- Kernel 2: MLP front, 1 cluster/block. Wave 0 does the bit-select
// (first 64 set bits of the 128 mask words, wave-parallel prefix scan —
// constant work, no tail) + gather; waves 1-3 prefetch W1/W2 meanwhile.
// (256,5): 68 VGPR + 32 AGPR ~= 100 <= 102 -> 5 blocks/CU. ----
__global__ __launch_bounds__(256, 5) void feat3d_mlp(
    const float* __restrict__ xyz,
    const unsigned long long* __restrict__ mask,
    const float* __restrict__ W1, const float* __restrict__ b1,
    const float* __restrict__ b2, const float* __restrict__ b3,
    const unsigned short* __restrict__ Wp,
    unsigned short* __restrict__ vdst,
    float* __restrict__ out)
{
    __shared__ __align__(16) unsigned char lds[26880];
    unsigned short* a2p = (unsigned short*)lds;            // h1 A-frags, 8 KB
    unsigned short* a3p = (unsigned short*)(lds + 8192);   // h2 A-frags, 16 KB
    float* ls_w1        = (float*)(lds + 24576);           // [64][4], 1 KB
    float* ls_g         = (float*)(lds + 25600);           // [64][4], 1 KB
    int*   ls_idx       = (int*)(lds + 26624);             // [64]

    const int t   = threadIdx.x;
    const int wv  = t >> 6;
    const int l   = t & 63;
    const int q   = l >> 4;
    const int r16 = l & 15;
    const int blk = blockIdx.x;                // cluster id cg
    const int b   = blk >> 9;
    const int m   = blk & 511;
    const float* xb = xyz + (size_t)b * (NN * 3);

    // All waves: prefetch W2 B-frags (one dwordx4 each) immediately.
    const v8s* W2f = (const v8s*)Wp;
    v8s bfr[2][2];
    #pragma unroll
    for (int kt = 0; kt < 2; ++kt)
        #pragma unroll
        for (int ni = 0; ni < 2; ++ni)
            bfr[kt][ni] = W2f[(kt*8 + 2*wv + ni)*64 + l];

    // Wave 1: stage W1^T + b1 while wave 0 selects.
    if (wv == 1) {
        ls_w1[l*4+0] = W1[l];
        ls_w1[l*4+1] = W1[64 + l];
        ls_w1[l*4+2] = W1[128 + l];
        ls_w1[l*4+3] = b1[l];
    }

    // ---- Wave 0: select first 64 set bits from mask[cg][0..127] ----
    if (wv == 0) {
        const float cx = xb[m*3+0], cy = xb[m*3+1], cz = xb[m*3+2];
        if (l < 3) out[blk*3 + l] = xb[m*3 + l];   // new_xyz

        const unsigned long long* mk = mask + (size_t)blk * 128;
        const unsigned long long wlo = mk[l];
        const unsigned long long whi = mk[64 + l];

        // lo round: words 0..63 (points 0..4095)
        const int pop = (int)__popcll(wlo);
        int inc = pop;
        #pragma unroll
        for (int d = 1; d < 64; d <<= 1) {
            const int u = __shfl_up(inc, d);
            if (l >= d) inc += u;
        }
        const int base = inc - pop;
        const int total_lo = __shfl(inc, 63);

        {
            unsigned long long bits = wlo;
            int bs = base;
            while (bits && bs < SS) {
                const int k = (int)__builtin_ctzll(bits);
                bits &= bits - 1;
                ls_idx[bs++] = l*64 + k;
            }
        }
        int cnt = total_lo;
        if (total_lo < SS) {   // hi round: words 64..127 (points 4096..8191)
            const int pop2 = (int)__popcll(whi);
            int inc2 = pop2;
            #pragma unroll
            for (int d = 1; d < 64; d <<= 1) {
                const int u = __shfl_up(inc2, d);
                if (l >= d) inc2 += u;
            }
            const int base2 = total_lo + inc2 - pop2;
            cnt = total_lo + __shfl(inc2, 63);
            unsigned long long bits = whi;
            int bs = base2;
            while (bits && bs < SS) {
                const int k = (int)__builtin_ctzll(bits);
                bits &= bits - 1;
                ls_idx[bs++] = (64 + l)*64 + k;
            }
        }
        if (cnt > SS) cnt = SS;

        // first valid index j0 (guaranteed in lo round: the center itself,
        // d2 = 0 < 4, index m < 512)
        const unsigned long long nz = __ballot(pop > 0);
        const int fw = (int)__builtin_ctzll(nz);
        const unsigned long long w0 = __shfl(wlo, fw);
        const int j0 = fw*64 + (int)__builtin_ctzll(w0);
        if (l >= cnt) ls_idx[l] = j0;          // pad

        // gather + g = (xyz[p]-c)/2 (exact f32, same ops as before)
        const int p = ls_idx[l];
        const float xp = xb[p*3+0], yp = xb[p*3+1], zp = xb[p*3+2];
        ls_g[l*4+0] = (xp - cx) * 0.5f;
        ls_g[l*4+1] = (yp - cy) * 0.5f;
        ls_g[l*4+2] = (zp - cz) * 0.5f;
        ls_g[l*4+3] = 0.f;
        out[OUT_IDX + (size_t)blk*SS + l] = (float)p;   // idx as float
    }
    __syncthreads();

    // ---- L1 (fp32) + pack h1 into A-frag layout: c = kt*32 + q*8 + j ----
    {
        const int s = wv*16 + r16;
        const float4 g4 = *(const float4*)&ls_g[s*4];
        #pragma unroll
        for (int kt = 0; kt < 2; ++kt) {
            union { unsigned short u[8]; v8s v; } fr;
            #pragma unroll
            for (int j = 0; j < 8; ++j) {
                const int c = kt*32 + q*8 + j;
                const float4 w = *(const float4*)&ls_w1[c*4];
                const float h = fmaf(g4.x, w.x, fmaf(g4.y, w.y,
                                fmaf(g4.z, w.z, w.w)));
                fr.u[j] = f2bf(fmaxf(h, 0.f));
            }
            *(v8s*)&a2p[((kt*4 + wv)*64 + l)*8] = fr.v;
        }
    }
    __syncthreads();

    // ---- L2 MFMA: h2 = relu(h1 @ W2 + b2). Wave wv owns nt {2wv, 2wv+1}. ----
    {
        const v4f z = {0.f, 0.f, 0.f, 0.f};
        v4f acc[4][2];
        #pragma unroll
        for (int mt = 0; mt < 4; ++mt) { acc[mt][0] = z; acc[mt][1] = z; }

        #pragma unroll
        for (int kt = 0; kt < 2; ++kt)
            #pragma unroll
            for (int mt = 0; mt < 4; ++mt) {
                const v8s a = *(const v8s*)&a2p[((kt*4 + mt)*64 + l)*8];
                acc[mt][0] = __builtin_amdgcn_mfma_f32_16x16x32_bf16(
                    a, bfr[kt][0], acc[mt][0], 0, 0, 0);
                acc[mt][1] = __builtin_amdgcn_mfma_f32_16x16x32_bf16(
                    a, bfr[kt][1], acc[mt][1], 0, 0, 0);
            }

        // Epilogue: +b2, relu, bf16, scatter into L3 A-frag layout.
        // C/D elem (mt,ni,rg): row s2 = mt*16+q*4+rg, col c2 = (2wv+ni)*16+r16.
        #pragma unroll
        for (int ni = 0; ni < 2; ++ni) {
            const int c2  = (2*wv + ni)*16 + r16;
            const float bias = b2[c2];
            const int kt3 = c2 >> 5;
            const int lhi = ((c2 >> 3) & 3) << 4;
            const int j3  = c2 & 7;
            #pragma unroll
            for (int mt = 0; mt < 4; ++mt)
                #pragma unroll
                for (int rg = 0; rg < 4; ++rg) {
                    const float h = fmaxf(acc[mt][ni][rg] + bias, 0.f);
                    const int s15 = q*4 + rg;
                    a3p[((kt3*4 + mt)*64 + (lhi | s15))*8 + j3] = f2bf(h);
                }
        }
    }
    __syncthreads();

    // ---- L3 MFMA in 2 N-passes (acc[4][2] bounds regs). Wave wv owns
    // nt {4wv..4wv+3}; W3 B-frags pipelined one kt ahead. Pool in regs. ----
    {
        const v8s* W3f = (const v8s*)(Wp + WS_W3);
        unsigned short* vrow = vdst + (size_t)blk * 256;

        #pragma unroll
        for (int np = 0; np < 2; ++np) {
            const int nt0 = 4*wv + 2*np;
            const v4f z = {0.f, 0.f, 0.f, 0.f};
            v4f acc[4][2];
            #pragma unroll
            for (int mt = 0; mt < 4; ++mt) { acc[mt][0] = z; acc[mt][1] = z; }

            v8s bb0 = W3f[(nt0    )*64 + l];        // kt = 0
            v8s bb1 = W3f[(nt0 + 1)*64 + l];
            #pragma unroll
            for (int kt = 0; kt < 4; ++kt) {
                v8s a[4];
                #pragma unroll
                for (int mt = 0; mt < 4; ++mt)
                    a[mt] = *(const v8s*)&a3p[((kt*4 + mt)*64 + l)*8];
                v8s nb0, nb1;
                if (kt < 3) {
                    nb0 = W3f[((kt+1)*16 + nt0    )*64 + l];
                    nb1 = W3f[((kt+1)*16 + nt0 + 1)*64 + l];
                }
                #pragma unroll
                for (int mt = 0; mt < 4; ++mt) {
                    acc[mt][0] = __builtin_amdgcn_mfma_f32_16x16x32_bf16(
                        a[mt], bb0, acc[mt][0], 0, 0, 0);
                    acc[mt][1] = __builtin_amdgcn_mfma_f32_16x16x32_bf16(
                        a[mt], bb1, acc[mt][1], 0, 0, 0);
                }
                if (kt < 3) { bb0 = nb0; bb1 = nb1; }
            }

            // Pool over samples (16 regs + cross-quad shfl); bias+relu after
            // pool (relu monotone, bias per-column => commutes). Store bf16 v.
            #pragma unroll
            for (int ni = 0; ni < 2; ++ni) {
                float mx = acc[0][ni][0];
                #pragma unroll
                for (int mt = 0; mt < 4; ++mt)
                    #pragma unroll
                    for (int rg = 0; rg < 4; ++rg)
                        mx = fmaxf(mx, acc[mt][ni][rg]);
                mx = fmaxf(mx, __shfl_xor(mx, 16));
                mx = fmaxf(mx, __shfl_xor(mx, 32));
                if (q == 0) {
                    const int c = (nt0 + ni)*16 + r16;
                    vrow[c] = f2bf(fmaxf(mx + b3[c], 0.f));
                }
            }
        }
    }
}

// ---- Kernel 3: tail — 16 clusters/block; W4/W5 read 256x fewer times.
// L4/L5 fp32; heads fused. ----
__global__ __launch_bounds__(256) void feat3d_tail(
    const unsigned short* __restrict__ vsrc,
    const float* __restrict__ W4, const float* __restrict__ b4,
    const float* __restrict__ W5, const float* __restrict__ b5,
    const float* __restrict__ Wa, const float* __restrict__ ba,
    const float* __restrict__ Wo, const float* __restrict__ bo,
    float* __restrict__ out)
{
    __shared__ __align__(16) float V[16][256];    // 16 KB
    __shared__ __align__(16) float H4[16][128];   // 8 KB
    __shared__ __align__(16) float H5[16][64];    // 4 KB

    const int t   = threadIdx.x;
    const int cl0 = blockIdx.x * 16;

    // Load V tile (bf16 -> f32), coalesced uint4 (8 shorts each, x2/thread).
    {
        const int i  = t >> 4;
        const int ch = t & 15;
        const uint4* src = (const uint4*)(vsrc + (size_t)(cl0 + i) * 256);
        #pragma unroll
        for (int h = 0; h < 2; ++h) {
            const uint4 r = src[ch*2 + h];
            const unsigned int u[4] = {r.x, r.y, r.z, r.w};
            #pragma unroll
            for (int j = 0; j < 4; ++j) {
                V[i][ch*16 + h*8 + 2*j]     = __uint_as_float(u[j] << 16);
                V[i][ch*16 + h*8 + 2*j + 1] = __uint_as_float(u[j] & 0xFFFF0000u);
            }
        }
    }
    __syncthreads();

    // L4: h4[i][c] = b4[c] + sum_k V[i][k] W4[k][c]; thread = (c, 8 clusters).
    {
        const int c  = t & 127;
        const int ih = t >> 7;
        float acc[8];
        #pragma unroll
        for (int i = 0; i < 8; ++i) acc[i] = b4[c];
        for (int k4 = 0; k4 < 64; ++k4) {
            const float w0 = W4[(4*k4+0)*128 + c];
            const float w1 = W4[(4*k4+1)*128 + c];
            const float w2 = W4[(4*k4+2)*128 + c];
            const float w3 = W4[(4*k4+3)*128 + c];
            #pragma unroll
            for (int i = 0; i < 8; ++i) {
                const float4 vv = *(const float4*)&V[ih*8 + i][4*k4];
                acc[i] = fmaf(vv.x, w0, fmaf(vv.y, w1,
                         fmaf(vv.z, w2, fmaf(vv.w, w3, acc[i]))));
            }
        }
        #pragma unroll
        for (int i = 0; i < 8; ++i) H4[ih*8 + i][c] = acc[i];
    }
    __syncthreads();

    // L5: h5[i][c] = b5[c] + sum_k H4[i][k] W5[k][c]; thread = (c, 4 clusters).
    {
        const int c  = t & 63;
        const int iq = t >> 6;
        float acc[4];
        #pragma unroll
        for (int i = 0; i < 4; ++i) acc[i] = b5[c];
        for (int k4 = 0; k4 < 32; ++k4) {
            const float w0 = W5[(4*k4+0)*64 + c];
            const float w1 = W5[(4*k4+1)*64 + c];
            const float w2 = W5[(4*k4+2)*64 + c];
            const float w3 = W5[(4*k4+3)*64 + c];
            #pragma unroll
            for (int i = 0; i < 4; ++i) {
                const float4 vv = *(const float4*)&H4[iq*4 + i][4*k4];
                acc[i] = fmaf(vv.x, w0, fmaf(vv.y, w1,
                         fmaf(vv.z, w2, fmaf(vv.w, w3, acc[i]))));
            }
        }
        #pragma unroll
        for (int i = 0; i < 4; ++i) H5[iq*4 + i][c] = acc[i];
    }
    __syncthreads();

    // Heads: wave wv handles clusters 4wv..4wv+3. attention = softplus(h5.Wa+ba);
    // orientation = atan2(o1,o0) (normalization is scale-invariant -> skipped).
    {
        const int wv = t >> 6, l = t & 63;
        const float wa  = Wa[l];
        const float wo0 = Wo[2*l + 0];
        const float wo1 = Wo[2*l + 1];
        #pragma unroll
        for (int i = 0; i < 4; ++i) {
            const float hv = H5[4*wv + i][l];
            float va = hv * wa;
            float v0 = hv * wo0;
            float v1 = hv * wo1;
            #pragma unroll
            for (int off = 32; off > 0; off >>= 1) {
                va += __shfl_down(va, off);
                v0 += __shfl_down(v0, off);
                v1 += __shfl_down(v1, off);
            }
            if (l == 0) {
                const int cg = cl0 + 4*wv + i;
                const float a = va + ba[0];
                out[OUT_ATT + cg] = fmaxf(a, 0.f) + log1pf(expf(-fabsf(a)));
                out[OUT_ORI + cg] = atan2f(v1 + bo[1], v0 + bo[0]);
            }
        }
    }
}

extern "C" void kernel_launch(void* const* d_in, const int* in_sizes, int n_in,
                              void* d_out, int out_size, void* d_ws, size_t ws_size,
                              hipStream_t stream) {
    const float* xyz = (const float*)d_in[0];
    const float* W1  = (const float*)d_in[1];
    const float* b1  = (const float*)d_in[2];
    const float* W2  = (const float*)d_in[3];
    const float* b2  = (const float*)d_in[4];
    const float* W3  = (const float*)d_in[5];
    const float* b3  = (const float*)d_in[6];
    const float* W4  = (const float*)d_in[7];
    const float* b4  = (const float*)d_in[8];
    const float* W5  = (const float*)d_in[9];
    const float* b5  = (const float*)d_in[10];
    const float* Wa  = (const float*)d_in[11];
    const float* ba  = (const float*)d_in[12];
    const float* Wo  = (const float*)d_in[13];
    const float* bo  = (const float*)d_in[14];

    unsigned short* ws = (unsigned short*)d_ws;
    unsigned long long* msk = (unsigned long long*)((char*)d_ws + WS_MASK_BYTES);

    pack_weights<<<dim3(20), dim3(256), 0, stream>>>(W2, W3, ws);
    feat3d_mask<<<dim3(8192), dim3(256), 0, stream>>>(xyz, msk);
    feat3d_mlp<<<dim3(NCLUST), dim3(256), 0, stream>>>(
        xyz, msk, W1, b1, b2, b3, ws, ws + WS_V, (float*)d_out);
    feat3d_tail<<<dim3(NCLUST/16), dim3(256), 0, stream>>>(
        ws + WS_V, W4, b4, W5, b5, Wa, ba, Wo, bo, (float*)d_out);
}

// Round 10
// 164.281 us; speedup vs baseline: 1.1719x; 1.0585x over previous
//
#include <hip/hip_runtime.h>
#include <math.h>

// Shapes fixed by setup_inputs(): B=8, N=8192, M=512 clusters, S=64 samples.
#define BB 8
#define NN 8192
#define MM 512
#define SS 64
#define NCLUST (BB*MM)                 // 4096

// d_out layout (flat, return order, all read back as f32):
// new_xyz[8*512*3] | idx(as float)[8*512*64] | attention[8*512] | orientation[8*512]
#define OUT_IDX   (BB*MM*3)            // 12288
#define OUT_ATT   (OUT_IDX + BB*MM*SS) // 274432
#define OUT_ORI   (OUT_ATT + BB*MM)    // 278528

// d_ws layout (ushort units unless noted):
// [0,8192)            W2 B-frags (bf16)
// [8192,40960)        W3 B-frags (bf16)
// [40960,1089536)     pooled v (bf16)  4096*256
// byte 2179072:       validity masks, u64[4096][128] = 4 MB
#define WS_W3 8192
#define WS_V  40960
#define WS_MASK_BYTES 2179072

typedef short v8s __attribute__((ext_vector_type(8)));   // 8 bf16 (MFMA A/B frag)
typedef float v4f __attribute__((ext_vector_type(4)));   // MFMA C/D frag

static __device__ __forceinline__ unsigned short f2bf(float x) {
    unsigned int u = __float_as_uint(x);
    u += 0x7FFFu + ((u >> 16) & 1u);     // round-to-nearest-even
    return (unsigned short)(u >> 16);
}

// ---- Kernel 0: pack W2 (64x128) and W3 (128x256) fp32 -> bf16 MFMA B-frag
// layout. B-frag lane l holds B[kt*32+(l>>4)*8+j][nt*16+(l&15)], j=0..7,
// stored contiguous (16 B/lane) so the MLP kernel loads one dwordx4/frag.
__global__ void pack_weights(const float* __restrict__ W2,
                             const float* __restrict__ W3,
                             unsigned short* __restrict__ ws)
{
    const int gid = blockIdx.x * 256 + threadIdx.x;    // 0..5119
    const float* W; unsigned short* dst; int N, kt, nt, lane;
    if (gid < 1024) {                   // W2: 16 tiles * 64 lanes
        W = W2; N = 128;
        const int tile = gid >> 6; lane = gid & 63;
        kt = tile >> 3; nt = tile & 7;
        dst = ws + (size_t)(tile * 64 + lane) * 8;
    } else {                            // W3: 64 tiles * 64 lanes
        const int g = gid - 1024;
        W = W3; N = 256;
        const int tile = g >> 6; lane = g & 63;
        kt = tile >> 4; nt = tile & 15;
        dst = ws + WS_W3 + (size_t)(tile * 64 + lane) * 8;
    }
    const int k0 = kt * 32 + (lane >> 4) * 8;
    const int n  = nt * 16 + (lane & 15);
    union { unsigned short u[8]; v8s v; } f;
    #pragma unroll
    for (int j = 0; j < 8; ++j) f.u[j] = f2bf(W[(k0 + j) * N + n]);
    *(v8s*)dst = f.v;
}

// ---- Kernel 1: validity masks. Block = (batch, 8-cluster group); scans all
// 8192 points (uniform work, no stragglers). Ballot words accumulate in an
// 8 KB LDS tile; one coalesced full-line writeback at the end (the R9 version
// did scattered 8-B stores -> 128-B RMW lines -> ~67 MB of traffic for 4 MB).
__global__ __launch_bounds__(256) void feat3d_mask(
    const float* __restrict__ xyz,
    unsigned long long* __restrict__ mask)
{
    __shared__ unsigned long long tile[8][128];    // 8 KB

    const int t   = threadIdx.x;
    const int l   = t & 63;
    const int wv  = t >> 6;
    const int blk = blockIdx.x;          // 512 = 8 batches * 64 groups
    const int b   = blk >> 6;
    const int grp = blk & 63;
    const int m0  = grp * 8;
    const float* xb = xyz + (size_t)b * (NN * 3);

    // Centers (block-uniform -> scalar loads).
    float cxs[8], cys[8], czs[8];
    #pragma unroll
    for (int i = 0; i < 8; ++i) {
        cxs[i] = xb[(m0+i)*3+0];
        cys[i] = xb[(m0+i)*3+1];
        czs[i] = xb[(m0+i)*3+2];
    }

    #pragma unroll 2
    for (int it = 0; it < 32; ++it) {
        const int p = it*256 + t;
        const float px = xb[p*3+0], py = xb[p*3+1], pz = xb[p*3+2];
        const int wsub = it*4 + wv;     // word index = p>>6
        #pragma unroll
        for (int i = 0; i < 8; ++i) {
            const float dx = px - cxs[i];
            const float dy = py - cys[i];
            const float dz = pz - czs[i];
            // no fma contraction: idx must be exact at the d2==4.0 boundary
            const float d2 = __fadd_rn(__fadd_rn(__fmul_rn(dx,dx),
                                 __fmul_rn(dy,dy)), __fmul_rn(dz,dz));
            const unsigned long long mk = __ballot(d2 < 4.0f);
            if (l == 0) tile[i][wsub] = mk;
        }
    }
    __syncthreads();

    // Writeback: thread t -> cluster i = t>>5, words w0..w0+3 (32 B contig;
    // each 32-thread group covers one 1 KB cluster row = full 128-B lines).
    {
        const int i  = t >> 5;
        const int w0 = (t & 31) * 4;
        unsigned long long* dst = mask + (size_t)(b*512 + m0 + i)*128 + w0;
        dst[0] = tile[i][w0+0];
        dst[1] = tile[i][w0+1];
        dst[2] = tile[i][w0+2];
        dst[3] = tile[i][w0+3];
    }
}

// ---- Kernel 2: MLP front, 1 cluster/block. Wave 0 does the bit-select
// (first 64 set bits of the 128 mask words, wave-parallel prefix scan)
// + gather; wave 1 stages W1 meanwhile.
// (256,4): 128-reg budget — peak live ~110 (acc[4][2] AGPR + bfr + frags),
// NO spills (R9's (256,5) bound spilled ~89 MB of scratch traffic). ----
__global__ __launch_bounds__(256, 4) void feat3d_mlp(
    const float* __restrict__ xyz,
    const unsigned long long* __restrict__ mask,
    const float* __restrict__ W1, const float* __restrict__ b1,
    const float* __restrict__ b2, const float* __restrict__ b3,
    const unsigned short* __restrict__ Wp,
    unsigned short* __restrict__ vdst,
    float* __restrict__ out)
{
    __shared__ __align__(16) unsigned char lds[26880];
    unsigned short* a2p = (unsigned short*)lds;            // h1 A-frags, 8 KB
    unsigned short* a3p = (unsigned short*)(lds + 8192);   // h2 A-frags, 16 KB
    float* ls_w1        = (float*)(lds + 24576);           // [64][4], 1 KB
    float* ls_g         = (float*)(lds + 25600);           // [64][4], 1 KB
    int*   ls_idx       = (int*)(lds + 26624);             // [64]

    const int t   = threadIdx.x;
    const int wv  = t >> 6;
    const int l   = t & 63;
    const int q   = l >> 4;
    const int r16 = l & 15;
    const int blk = blockIdx.x;                // cluster id cg
    const int b   = blk >> 9;
    const int m   = blk & 511;
    const float* xb = xyz + (size_t)b * (NN * 3);

    // All waves: prefetch W2 B-frags (one dwordx4 each) immediately.
    const v8s* W2f = (const v8s*)Wp;
    v8s bfr[2][2];
    #pragma unroll
    for (int kt = 0; kt < 2; ++kt)
        #pragma unroll
        for (int ni = 0; ni < 2; ++ni)
            bfr[kt][ni] = W2f[(kt*8 + 2*wv + ni)*64 + l];

    // Wave 1: stage W1^T + b1 while wave 0 selects.
    if (wv == 1) {
        ls_w1[l*4+0] = W1[l];
        ls_w1[l*4+1] = W1[64 + l];
        ls_w1[l*4+2] = W1[128 + l];
        ls_w1[l*4+3] = b1[l];
    }

    // ---- Wave 0: select first 64 set bits from mask[cg][0..127] ----
    if (wv == 0) {
        const float cx = xb[m*3+0], cy = xb[m*3+1], cz = xb[m*3+2];
        if (l < 3) out[blk*3 + l] = xb[m*3 + l];   // new_xyz

        const unsigned long long* mk = mask + (size_t)blk * 128;
        const unsigned long long wlo = mk[l];
        const unsigned long long whi = mk[64 + l];

        // lo round: words 0..63 (points 0..4095)
        const int pop = (int)__popcll(wlo);
        int inc = pop;
        #pragma unroll
        for (int d = 1; d < 64; d <<= 1) {
            const int u = __shfl_up(inc, d);
            if (l >= d) inc += u;
        }
        const int base = inc - pop;
        const int total_lo = __shfl(inc, 63);

        {
            unsigned long long bits = wlo;
            int bs = base;
            while (bits && bs < SS) {
                const int k = (int)__builtin_ctzll(bits);
                bits &= bits - 1;
                ls_idx[bs++] = l*64 + k;
            }
        }
        int cnt = total_lo;
        if (total_lo < SS) {   // hi round: words 64..127 (points 4096..8191)
            const int pop2 = (int)__popcll(whi);
            int inc2 = pop2;
            #pragma unroll
            for (int d = 1; d < 64; d <<= 1) {
                const int u = __shfl_up(inc2, d);
                if (l >= d) inc2 += u;
            }
            const int base2 = total_lo + inc2 - pop2;
            cnt = total_lo + __shfl(inc2, 63);
            unsigned long long bits = whi;
            int bs = base2;
            while (bits && bs < SS) {
                const int k = (int)__builtin_ctzll(bits);
                bits &= bits - 1;
                ls_idx[bs++] = (64 + l)*64 + k;
            }
        }
        if (cnt > SS) cnt = SS;

        // first valid index j0 (guaranteed in lo round: the center itself,
        // d2 = 0 < 4, index m < 512)
        const unsigned long long nz = __ballot(pop > 0);
        const int fw = (int)__builtin_ctzll(nz);
        const unsigned long long w0 = __shfl(wlo, fw);
        const int j0 = fw*64 + (int)__builtin_ctzll(w0);
        if (l >= cnt) ls_idx[l] = j0;          // pad

        // gather + g = (xyz[p]-c)/2 (exact f32, same ops as before)
        const int p = ls_idx[l];
        const float xp = xb[p*3+0], yp = xb[p*3+1], zp = xb[p*3+2];
        ls_g[l*4+0] = (xp - cx) * 0.5f;
        ls_g[l*4+1] = (yp - cy) * 0.5f;
        ls_g[l*4+2] = (zp - cz) * 0.5f;
        ls_g[l*4+3] = 0.f;
        out[OUT_IDX + (size_t)blk*SS + l] = (float)p;   // idx as float
    }
    __syncthreads();

    // ---- L1 (fp32) + pack h1 into A-frag layout: c = kt*32 + q*8 + j ----
    {
        const int s = wv*16 + r16;
        const float4 g4 = *(const float4*)&ls_g[s*4];
        #pragma unroll
        for (int kt = 0; kt < 2; ++kt) {
            union { unsigned short u[8]; v8s v; } fr;
            #pragma unroll
            for (int j = 0; j < 8; ++j) {
                const int c = kt*32 + q*8 + j;
                const float4 w = *(const float4*)&ls_w1[c*4];
                const float h = fmaf(g4.x, w.x, fmaf(g4.y, w.y,
                                fmaf(g4.z, w.z, w.w)));
                fr.u[j] = f2bf(fmaxf(h, 0.f));
            }
            *(v8s*)&a2p[((kt*4 + wv)*64 + l)*8] = fr.v;
        }
    }
    __syncthreads();

    // ---- L2 MFMA: h2 = relu(h1 @ W2 + b2). Wave wv owns nt {2wv, 2wv+1}. ----
    {
        const v4f z = {0.f, 0.f, 0.f, 0.f};
        v4f acc[4][2];
        #pragma unroll
        for (int mt = 0; mt < 4; ++mt) { acc[mt][0] = z; acc[mt][1] = z; }

        #pragma unroll
        for (int kt = 0; kt < 2; ++kt)
            #pragma unroll
            for (int mt = 0; mt < 4; ++mt) {
                const v8s a = *(const v8s*)&a2p[((kt*4 + mt)*64 + l)*8];
                acc[mt][0] = __builtin_amdgcn_mfma_f32_16x16x32_bf16(
                    a, bfr[kt][0], acc[mt][0], 0, 0, 0);
                acc[mt][1] = __builtin_amdgcn_mfma_f32_16x16x32_bf16(
                    a, bfr[kt][1], acc[mt][1], 0, 0, 0);
            }

        // Epilogue: +b2, relu, bf16, scatter into L3 A-frag layout.
        // C/D elem (mt,ni,rg): row s2 = mt*16+q*4+rg, col c2 = (2wv+ni)*16+r16.
        #pragma unroll
        for (int ni = 0; ni < 2; ++ni) {
            const int c2  = (2*wv + ni)*16 + r16;
            const float bias = b2[c2];
            const int kt3 = c2 >> 5;
            const int lhi = ((c2 >> 3) & 3) << 4;
            const int j3  = c2 & 7;
            #pragma unroll
            for (int mt = 0; mt < 4; ++mt)
                #pragma unroll
                for (int rg = 0; rg < 4; ++rg) {
                    const float h = fmaxf(acc[mt][ni][rg] + bias, 0.f);
                    const int s15 = q*4 + rg;
                    a3p[((kt3*4 + mt)*64 + (lhi | s15))*8 + j3] = f2bf(h);
                }
        }
    }
    __syncthreads();

    // ---- L3 MFMA in 2 N-passes (acc[4][2] bounds regs). Wave wv owns
    // nt {4wv..4wv+3}; W3 B-frags pipelined one kt ahead. Pool in regs. ----
    {
        const v8s* W3f = (const v8s*)(Wp + WS_W3);
        unsigned short* vrow = vdst + (size_t)blk * 256;

        #pragma unroll
        for (int np = 0; np < 2; ++np) {
            const int nt0 = 4*wv + 2*np;
            const v4f z = {0.f, 0.f, 0.f, 0.f};
            v4f acc[4][2];
            #pragma unroll
            for (int mt = 0; mt < 4; ++mt) { acc[mt][0] = z; acc[mt][1] = z; }

            v8s bb0 = W3f[(nt0    )*64 + l];        // kt = 0
            v8s bb1 = W3f[(nt0 + 1)*64 + l];
            #pragma unroll
            for (int kt = 0; kt < 4; ++kt) {
                v8s a[4];
                #pragma unroll
                for (int mt = 0; mt < 4; ++mt)
                    a[mt] = *(const v8s*)&a3p[((kt*4 + mt)*64 + l)*8];
                v8s nb0, nb1;
                if (kt < 3) {
                    nb0 = W3f[((kt+1)*16 + nt0    )*64 + l];
                    nb1 = W3f[((kt+1)*16 + nt0 + 1)*64 + l];
                }
                #pragma unroll
                for (int mt = 0; mt < 4; ++mt) {
                    acc[mt][0] = __builtin_amdgcn_mfma_f32_16x16x32_bf16(
                        a[mt], bb0, acc[mt][0], 0, 0, 0);
                    acc[mt][1] = __builtin_amdgcn_mfma_f32_16x16x32_bf16(
                        a[mt], bb1, acc[mt][1], 0, 0, 0);
                }
                if (kt < 3) { bb0 = nb0; bb1 = nb1; }
            }

            // Pool over samples (16 regs + cross-quad shfl); bias+relu after
            // pool (relu monotone, bias per-column => commutes). Store bf16 v.
            #pragma unroll
            for (int ni = 0; ni < 2; ++ni) {
                float mx = acc[0][ni][0];
                #pragma unroll
                for (int mt = 0; mt < 4; ++mt)
                    #pragma unroll
                    for (int rg = 0; rg < 4; ++rg)
                        mx = fmaxf(mx, acc[mt][ni][rg]);
                mx = fmaxf(mx, __shfl_xor(mx, 16));
                mx = fmaxf(mx, __shfl_xor(mx, 32));
                if (q == 0) {
                    const int c = (nt0 + ni)*16 + r16;
                    vrow[c] = f2bf(fmaxf(mx + b3[c], 0.f));
                }
            }
        }
    }
}

// ---- Kernel 3: tail — 16 clusters/block; W4/W5 read 256x fewer times.
// L4/L5 fp32; heads fused. ----
__global__ __launch_bounds__(256) void feat3d_tail(
    const unsigned short* __restrict__ vsrc,
    const float* __restrict__ W4, const float* __restrict__ b4,
    const float* __restrict__ W5, const float* __restrict__ b5,
    const float* __restrict__ Wa, const float* __restrict__ ba,
    const float* __restrict__ Wo, const float* __restrict__ bo,
    float* __restrict__ out)
{
    __shared__ __align__(16) float V[16][256];    // 16 KB
    __shared__ __align__(16) float H4[16][128];   // 8 KB
    __shared__ __align__(16) float H5[16][64];    // 4 KB

    const int t   = threadIdx.x;
    const int cl0 = blockIdx.x * 16;

    // Load V tile (bf16 -> f32), coalesced uint4 (8 shorts each, x2/thread).
    {
        const int i  = t >> 4;
        const int ch = t & 15;
        const uint4* src = (const uint4*)(vsrc + (size_t)(cl0 + i) * 256);
        #pragma unroll
        for (int h = 0; h < 2; ++h) {
            const uint4 r = src[ch*2 + h];
            const unsigned int u[4] = {r.x, r.y, r.z, r.w};
            #pragma unroll
            for (int j = 0; j < 4; ++j) {
                V[i][ch*16 + h*8 + 2*j]     = __uint_as_float(u[j] << 16);
                V[i][ch*16 + h*8 + 2*j + 1] = __uint_as_float(u[j] & 0xFFFF0000u);
            }
        }
    }
    __syncthreads();

    // L4: h4[i][c] = b4[c] + sum_k V[i][k] W4[k][c]; thread = (c, 8 clusters).
    {
        const int c  = t & 127;
        const int ih = t >> 7;
        float acc[8];
        #pragma unroll
        for (int i = 0; i < 8; ++i) acc[i] = b4[c];
        for (int k4 = 0; k4 < 64; ++k4) {
            const float w0 = W4[(4*k4+0)*128 + c];
            const float w1 = W4[(4*k4+1)*128 + c];
            const float w2 = W4[(4*k4+2)*128 + c];
            const float w3 = W4[(4*k4+3)*128 + c];
            #pragma unroll
            for (int i = 0; i < 8; ++i) {
                const float4 vv = *(const float4*)&V[ih*8 + i][4*k4];
                acc[i] = fmaf(vv.x, w0, fmaf(vv.y, w1,
                         fmaf(vv.z, w2, fmaf(vv.w, w3, acc[i]))));
            }
        }
        #pragma unroll
        for (int i = 0; i < 8; ++i) H4[ih*8 + i][c] = acc[i];
    }
    __syncthreads();

    // L5: h5[i][c] = b5[c] + sum_k H4[i][k] W5[k][c]; thread = (c, 4 clusters).
    {
        const int c  = t & 63;
        const int iq = t >> 6;
        float acc[4];
        #pragma unroll
        for (int i = 0; i < 4; ++i) acc[i] = b5[c];
        for (int k4 = 0; k4 < 32; ++k4) {
            const float w0 = W5[(4*k4+0)*64 + c];
            const float w1 = W5[(4*k4+1)*64 + c];
            const float w2 = W5[(4*k4+2)*64 + c];
            const float w3 = W5[(4*k4+3)*64 + c];
            #pragma unroll
            for (int i = 0; i < 4; ++i) {
                const float4 vv = *(const float4*)&H4[iq*4 + i][4*k4];
                acc[i] = fmaf(vv.x, w0, fmaf(vv.y, w1,
                         fmaf(vv.z, w2, fmaf(vv.w, w3, acc[i]))));
            }
        }
        #pragma unroll
        for (int i = 0; i < 4; ++i) H5[iq*4 + i][c] = acc[i];
    }
    __syncthreads();

    // Heads: wave wv handles clusters 4wv..4wv+3. attention = softplus(h5.Wa+ba);
    // orientation = atan2(o1,o0) (normalization is scale-invariant -> skipped).
    {
        const int wv = t >> 6, l = t & 63;
        const float wa  = Wa[l];
        const float wo0 = Wo[2*l + 0];
        const float wo1 = Wo[2*l + 1];
        #pragma unroll
        for (int i = 0; i < 4; ++i) {
            const float hv = H5[4*wv + i][l];
            float va = hv * wa;
            float v0 = hv * wo0;
            float v1 = hv * wo1;
            #pragma unroll
            for (int off = 32; off > 0; off >>= 1) {
                va += __shfl_down(va, off);
                v0 += __shfl_down(v0, off);
                v1 += __shfl_down(v1, off);
            }
            if (l == 0) {
                const int cg = cl0 + 4*wv + i;
                const float a = va + ba[0];
                out[OUT_ATT + cg] = fmaxf(a, 0.f) + log1pf(expf(-fabsf(a)));
                out[OUT_ORI + cg] = atan2f(v1 + bo[1], v0 + bo[0]);
            }
        }
    }
}

extern "C" void kernel_launch(void* const* d_in, const int* in_sizes, int n_in,
                              void* d_out, int out_size, void* d_ws, size_t ws_size,
                              hipStream_t stream) {
    const float* xyz = (const float*)d_in[0];
    const float* W1  = (const float*)d_in[1];
    const float* b1  = (const float*)d_in[2];
    const float* W2  = (const float*)d_in[3];
    const float* b2  = (const float*)d_in[4];
    const float* W3  = (const float*)d_in[5];
    const float* b3  = (const float*)d_in[6];
    const float* W4  = (const float*)d_in[7];
    const float* b4  = (const float*)d_in[8];
    const float* W5  = (const float*)d_in[9];
    const float* b5  = (const float*)d_in[10];
    const float* Wa  = (const float*)d_in[11];
    const float* ba  = (const float*)d_in[12];
    const float* Wo  = (const float*)d_in[13];
    const float* bo  = (const float*)d_in[14];

    unsigned short* ws = (unsigned short*)d_ws;
    unsigned long long* msk = (unsigned long long*)((char*)d_ws + WS_MASK_BYTES);

    pack_weights<<<dim3(20), dim3(256), 0, stream>>>(W2, W3, ws);
    feat3d_mask<<<dim3(512), dim3(256), 0, stream>>>(xyz, msk);
    feat3d_mlp<<<dim3(NCLUST), dim3(256), 0, stream>>>(
        xyz, msk, W1, b1, b2, b3, ws, ws + WS_V, (float*)d_out);
    feat3d_tail<<<dim3(NCLUST/16), dim3(256), 0, stream>>>(
        ws + WS_V, W4, b4, W5, b5, Wa, ba, Wo, bo, (float*)d_out);
}

// Round 11
// 159.545 us; speedup vs baseline: 1.2067x; 1.0297x over previous
//
#include <hip/hip_runtime.h>
#include <math.h>

// Shapes fixed by setup_inputs(): B=8, N=8192, M=512 clusters, S=64 samples.
#define BB 8
#define NN 8192
#define MM 512
#define SS 64
#define NCLUST (BB*MM)                 // 4096

// d_out layout (flat, return order, all read back as f32):
// new_xyz[8*512*3] | idx(as float)[8*512*64] | attention[8*512] | orientation[8*512]
#define OUT_IDX   (BB*MM*3)            // 12288
#define OUT_ATT   (OUT_IDX + BB*MM*SS) // 274432
#define OUT_ORI   (OUT_ATT + BB*MM)    // 278528

// d_ws layout:
// ushort[0,8192)        W2 B-frags (bf16)
// ushort[8192,40960)    W3 B-frags (bf16)
// ushort[40960,1089536) pooled v (bf16)  4096*256
// byte 2179072:         validity masks, u64[4096][128] = 4 MB
// byte 6373376:         g (f32) 4096*64*4 floats = 4 MB
#define WS_W3 8192
#define WS_V  40960
#define WS_MASK_BYTES 2179072
#define WS_G_BYTES    6373376

typedef short v8s __attribute__((ext_vector_type(8)));   // 8 bf16 (MFMA A/B frag)
typedef float v4f __attribute__((ext_vector_type(4)));   // MFMA C/D frag

static __device__ __forceinline__ unsigned short f2bf(float x) {
    unsigned int u = __float_as_uint(x);
    u += 0x7FFFu + ((u >> 16) & 1u);     // round-to-nearest-even
    return (unsigned short)(u >> 16);
}

// ---- Kernel 0: pack W2 (64x128) and W3 (128x256) fp32 -> bf16 MFMA B-frag
// layout. B-frag lane l holds B[kt*32+(l>>4)*8+j][nt*16+(l&15)], j=0..7,
// stored contiguous (16 B/lane) so the MLP kernel loads one dwordx4/frag.
__global__ void pack_weights(const float* __restrict__ W2,
                             const float* __restrict__ W3,
                             unsigned short* __restrict__ ws)
{
    const int gid = blockIdx.x * 256 + threadIdx.x;    // 0..5119
    const float* W; unsigned short* dst; int N, kt, nt, lane;
    if (gid < 1024) {                   // W2: 16 tiles * 64 lanes
        W = W2; N = 128;
        const int tile = gid >> 6; lane = gid & 63;
        kt = tile >> 3; nt = tile & 7;
        dst = ws + (size_t)(tile * 64 + lane) * 8;
    } else {                            // W3: 64 tiles * 64 lanes
        const int g = gid - 1024;
        W = W3; N = 256;
        const int tile = g >> 6; lane = g & 63;
        kt = tile >> 4; nt = tile & 15;
        dst = ws + WS_W3 + (size_t)(tile * 64 + lane) * 8;
    }
    const int k0 = kt * 32 + (lane >> 4) * 8;
    const int n  = nt * 16 + (lane & 15);
    union { unsigned short u[8]; v8s v; } f;
    #pragma unroll
    for (int j = 0; j < 8; ++j) f.u[j] = f2bf(W[(k0 + j) * N + n]);
    *(v8s*)dst = f.v;
}

// ---- Kernel 1: validity masks. Block = (batch, 8-cluster group); scans all
// 8192 points (uniform work). Ballot words accumulate in LDS; one coalesced
// full-line writeback (scattered 8-B stores would cause 128-B RMW lines).
__global__ __launch_bounds__(256) void feat3d_mask(
    const float* __restrict__ xyz,
    unsigned long long* __restrict__ mask)
{
    __shared__ unsigned long long tile[8][128];    // 8 KB

    const int t   = threadIdx.x;
    const int l   = t & 63;
    const int wv  = t >> 6;
    const int blk = blockIdx.x;          // 512 = 8 batches * 64 groups
    const int b   = blk >> 6;
    const int grp = blk & 63;
    const int m0  = grp * 8;
    const float* xb = xyz + (size_t)b * (NN * 3);

    float cxs[8], cys[8], czs[8];
    #pragma unroll
    for (int i = 0; i < 8; ++i) {
        cxs[i] = xb[(m0+i)*3+0];
        cys[i] = xb[(m0+i)*3+1];
        czs[i] = xb[(m0+i)*3+2];
    }

    #pragma unroll 2
    for (int it = 0; it < 32; ++it) {
        const int p = it*256 + t;
        const float px = xb[p*3+0], py = xb[p*3+1], pz = xb[p*3+2];
        const int wsub = it*4 + wv;     // word index = p>>6
        #pragma unroll
        for (int i = 0; i < 8; ++i) {
            const float dx = px - cxs[i];
            const float dy = py - cys[i];
            const float dz = pz - czs[i];
            // no fma contraction: idx must be exact at the d2==4.0 boundary
            const float d2 = __fadd_rn(__fadd_rn(__fmul_rn(dx,dx),
                                 __fmul_rn(dy,dy)), __fmul_rn(dz,dz));
            const unsigned long long mk = __ballot(d2 < 4.0f);
            if (l == 0) tile[i][wsub] = mk;
        }
    }
    __syncthreads();

    {
        const int i  = t >> 5;
        const int w0 = (t & 31) * 4;
        unsigned long long* dst = mask + (size_t)(b*512 + m0 + i)*128 + w0;
        dst[0] = tile[i][w0+0];
        dst[1] = tile[i][w0+1];
        dst[2] = tile[i][w0+2];
        dst[3] = tile[i][w0+3];
    }
}

// ---- Kernel 2: select + gather, ONE WAVE PER CLUSTER (constant work — 128
// mask words regardless of geometry; no straggler). No barriers. Extracts the
// first 64 set bits via wave prefix-scan, pads with the first valid point,
// gathers xyz and writes g (f32, exact) + idx + new_xyz. ----
__global__ __launch_bounds__(256) void feat3d_select(
    const float* __restrict__ xyz,
    const unsigned long long* __restrict__ mask,
    float* __restrict__ gws,
    float* __restrict__ out)
{
    __shared__ int sidx[4][64];          // per-wave slots (wave-private)

    const int t  = threadIdx.x;
    const int wv = t >> 6;
    const int l  = t & 63;
    const int cg = blockIdx.x * 4 + wv;  // this wave's cluster
    const int b  = cg >> 9;
    const int m  = cg & 511;
    const float* xb = xyz + (size_t)b * (NN * 3);

    const float cx = xb[m*3+0], cy = xb[m*3+1], cz = xb[m*3+2];
    if (l < 3) out[cg*3 + l] = xb[m*3 + l];   // new_xyz

    const unsigned long long* mk = mask + (size_t)cg * 128;
    const unsigned long long wlo = mk[l];
    const unsigned long long whi = mk[64 + l];

    // lo round: words 0..63 (points 0..4095)
    const int pop = (int)__popcll(wlo);
    int inc = pop;
    #pragma unroll
    for (int d = 1; d < 64; d <<= 1) {
        const int u = __shfl_up(inc, d);
        if (l >= d) inc += u;
    }
    const int base = inc - pop;
    const int total_lo = __shfl(inc, 63);

    {
        unsigned long long bits = wlo;
        int bs = base;
        while (bits && bs < SS) {
            const int k = (int)__builtin_ctzll(bits);
            bits &= bits - 1;
            sidx[wv][bs++] = l*64 + k;
        }
    }
    int cnt = total_lo;
    if (total_lo < SS) {    // hi round: words 64..127 (points 4096..8191)
        const int pop2 = (int)__popcll(whi);
        int inc2 = pop2;
        #pragma unroll
        for (int d = 1; d < 64; d <<= 1) {
            const int u = __shfl_up(inc2, d);
            if (l >= d) inc2 += u;
        }
        const int base2 = total_lo + inc2 - pop2;
        cnt = total_lo + __shfl(inc2, 63);
        unsigned long long bits = whi;
        int bs = base2;
        while (bits && bs < SS) {
            const int k = (int)__builtin_ctzll(bits);
            bits &= bits - 1;
            sidx[wv][bs++] = (64 + l)*64 + k;
        }
    }
    if (cnt > SS) cnt = SS;

    // first valid index j0 (guaranteed in lo round: the center itself,
    // d2 = 0 < 4, index m < 512)
    const unsigned long long nz = __ballot(pop > 0);
    const int fw = (int)__builtin_ctzll(nz);
    const unsigned long long w0 = __shfl(wlo, fw);
    const int j0 = fw*64 + (int)__builtin_ctzll(w0);
    if (l >= cnt) sidx[wv][l] = j0;       // pad

    // gather + g = (xyz[p]-c)/2 (exact f32, same ops as before); same-wave
    // LDS write->read: compiler orders via lgkmcnt, no barrier needed.
    const int p = sidx[wv][l];
    const float xp = xb[p*3+0], yp = xb[p*3+1], zp = xb[p*3+2];
    float4* gdst = (float4*)(gws + (size_t)cg * 256);
    gdst[l] = make_float4((xp - cx)*0.5f, (yp - cy)*0.5f, (zp - cz)*0.5f, 0.f);
    out[OUT_IDX + (size_t)cg*SS + l] = (float)p;    // idx as float
}

// ---- Kernel 3: pure-MFMA MLP front, 1 cluster/block. g loaded per-thread
// (coalesced float4) — no serial select phase, all 4 waves work immediately.
// (256,4): 128-reg budget, no spills (R9: (256,5) spilled 89 MB). ----
__global__ __launch_bounds__(256, 4) void feat3d_mlp(
    const float* __restrict__ gws,
    const float* __restrict__ W1, const float* __restrict__ b1,
    const float* __restrict__ b2, const float* __restrict__ b3,
    const unsigned short* __restrict__ Wp,
    unsigned short* __restrict__ vdst)
{
    __shared__ __align__(16) unsigned char lds[25600];
    unsigned short* a2p = (unsigned short*)lds;            // h1 A-frags, 8 KB
    unsigned short* a3p = (unsigned short*)(lds + 8192);   // h2 A-frags, 16 KB
    float* ls_w1        = (float*)(lds + 24576);           // [64][4], 1 KB

    const int t   = threadIdx.x;
    const int wv  = t >> 6;
    const int l   = t & 63;
    const int q   = l >> 4;
    const int r16 = l & 15;
    const int blk = blockIdx.x;                // cluster id

    // Prefetch W2 B-frags (one dwordx4 each) immediately.
    const v8s* W2f = (const v8s*)Wp;
    v8s bfr[2][2];
    #pragma unroll
    for (int kt = 0; kt < 2; ++kt)
        #pragma unroll
        for (int ni = 0; ni < 2; ++ni)
            bfr[kt][ni] = W2f[(kt*8 + 2*wv + ni)*64 + l];

    // This thread's g row (s = wv*16 + r16); quads share rows (cache bcast).
    const int s = wv*16 + r16;
    const float4 g4 = *(const float4*)(gws + (size_t)blk*256 + s*4);

    // Stage W1^T + b1.
    if (t < 64) {
        ls_w1[t*4+0] = W1[t];
        ls_w1[t*4+1] = W1[64 + t];
        ls_w1[t*4+2] = W1[128 + t];
        ls_w1[t*4+3] = b1[t];
    }
    __syncthreads();

    // ---- L1 (fp32) + pack h1 into A-frag layout: c = kt*32 + q*8 + j ----
    {
        #pragma unroll
        for (int kt = 0; kt < 2; ++kt) {
            union { unsigned short u[8]; v8s v; } fr;
            #pragma unroll
            for (int j = 0; j < 8; ++j) {
                const int c = kt*32 + q*8 + j;
                const float4 w = *(const float4*)&ls_w1[c*4];
                const float h = fmaf(g4.x, w.x, fmaf(g4.y, w.y,
                                fmaf(g4.z, w.z, w.w)));
                fr.u[j] = f2bf(fmaxf(h, 0.f));
            }
            *(v8s*)&a2p[((kt*4 + wv)*64 + l)*8] = fr.v;
        }
    }
    __syncthreads();

    // ---- L2 MFMA: h2 = relu(h1 @ W2 + b2). Wave wv owns nt {2wv, 2wv+1}. ----
    {
        const v4f z = {0.f, 0.f, 0.f, 0.f};
        v4f acc[4][2];
        #pragma unroll
        for (int mt = 0; mt < 4; ++mt) { acc[mt][0] = z; acc[mt][1] = z; }

        #pragma unroll
        for (int kt = 0; kt < 2; ++kt)
            #pragma unroll
            for (int mt = 0; mt < 4; ++mt) {
                const v8s a = *(const v8s*)&a2p[((kt*4 + mt)*64 + l)*8];
                acc[mt][0] = __builtin_amdgcn_mfma_f32_16x16x32_bf16(
                    a, bfr[kt][0], acc[mt][0], 0, 0, 0);
                acc[mt][1] = __builtin_amdgcn_mfma_f32_16x16x32_bf16(
                    a, bfr[kt][1], acc[mt][1], 0, 0, 0);
            }

        // Epilogue: +b2, relu, bf16, scatter into L3 A-frag layout.
        // C/D elem (mt,ni,rg): row s2 = mt*16+q*4+rg, col c2 = (2wv+ni)*16+r16.
        #pragma unroll
        for (int ni = 0; ni < 2; ++ni) {
            const int c2  = (2*wv + ni)*16 + r16;
            const float bias = b2[c2];
            const int kt3 = c2 >> 5;
            const int lhi = ((c2 >> 3) & 3) << 4;
            const int j3  = c2 & 7;
            #pragma unroll
            for (int mt = 0; mt < 4; ++mt)
                #pragma unroll
                for (int rg = 0; rg < 4; ++rg) {
                    const float h = fmaxf(acc[mt][ni][rg] + bias, 0.f);
                    const int s15 = q*4 + rg;
                    a3p[((kt3*4 + mt)*64 + (lhi | s15))*8 + j3] = f2bf(h);
                }
        }
    }
    __syncthreads();

    // ---- L3 MFMA in 2 N-passes (acc[4][2] bounds regs). Wave wv owns
    // nt {4wv..4wv+3}; W3 B-frags pipelined one kt ahead. Pool in regs. ----
    {
        const v8s* W3f = (const v8s*)(Wp + WS_W3);
        unsigned short* vrow = vdst + (size_t)blk * 256;

        #pragma unroll
        for (int np = 0; np < 2; ++np) {
            const int nt0 = 4*wv + 2*np;
            const v4f z = {0.f, 0.f, 0.f, 0.f};
            v4f acc[4][2];
            #pragma unroll
            for (int mt = 0; mt < 4; ++mt) { acc[mt][0] = z; acc[mt][1] = z; }

            v8s bb0 = W3f[(nt0    )*64 + l];        // kt = 0
            v8s bb1 = W3f[(nt0 + 1)*64 + l];
            #pragma unroll
            for (int kt = 0; kt < 4; ++kt) {
                v8s a[4];
                #pragma unroll
                for (int mt = 0; mt < 4; ++mt)
                    a[mt] = *(const v8s*)&a3p[((kt*4 + mt)*64 + l)*8];
                v8s nb0, nb1;
                if (kt < 3) {
                    nb0 = W3f[((kt+1)*16 + nt0    )*64 + l];
                    nb1 = W3f[((kt+1)*16 + nt0 + 1)*64 + l];
                }
                #pragma unroll
                for (int mt = 0; mt < 4; ++mt) {
                    acc[mt][0] = __builtin_amdgcn_mfma_f32_16x16x32_bf16(
                        a[mt], bb0, acc[mt][0], 0, 0, 0);
                    acc[mt][1] = __builtin_amdgcn_mfma_f32_16x16x32_bf16(
                        a[mt], bb1, acc[mt][1], 0, 0, 0);
                }
                if (kt < 3) { bb0 = nb0; bb1 = nb1; }
            }

            // Pool over samples (16 regs + cross-quad shfl); bias+relu after
            // pool (relu monotone, bias per-column => commutes). Store bf16 v.
            #pragma unroll
            for (int ni = 0; ni < 2; ++ni) {
                float mx = acc[0][ni][0];
                #pragma unroll
                for (int mt = 0; mt < 4; ++mt)
                    #pragma unroll
                    for (int rg = 0; rg < 4; ++rg)
                        mx = fmaxf(mx, acc[mt][ni][rg]);
                mx = fmaxf(mx, __shfl_xor(mx, 16));
                mx = fmaxf(mx, __shfl_xor(mx, 32));
                if (q == 0) {
                    const int c = (nt0 + ni)*16 + r16;
                    vrow[c] = f2bf(fmaxf(mx + b3[c], 0.f));
                }
            }
        }
    }
}

// ---- Kernel 4: tail — 16 clusters/block; W4/W5 read 256x fewer times.
// L4/L5 fp32; heads fused. ----
__global__ __launch_bounds__(256) void feat3d_tail(
    const unsigned short* __restrict__ vsrc,
    const float* __restrict__ W4, const float* __restrict__ b4,
    const float* __restrict__ W5, const float* __restrict__ b5,
    const float* __restrict__ Wa, const float* __restrict__ ba,
    const float* __restrict__ Wo, const float* __restrict__ bo,
    float* __restrict__ out)
{
    __shared__ __align__(16) float V[16][256];    // 16 KB
    __shared__ __align__(16) float H4[16][128];   // 8 KB
    __shared__ __align__(16) float H5[16][64];    // 4 KB

    const int t   = threadIdx.x;
    const int cl0 = blockIdx.x * 16;

    // Load V tile (bf16 -> f32), coalesced uint4 (8 shorts each, x2/thread).
    {
        const int i  = t >> 4;
        const int ch = t & 15;
        const uint4* src = (const uint4*)(vsrc + (size_t)(cl0 + i) * 256);
        #pragma unroll
        for (int h = 0; h < 2; ++h) {
            const uint4 r = src[ch*2 + h];
            const unsigned int u[4] = {r.x, r.y, r.z, r.w};
            #pragma unroll
            for (int j = 0; j < 4; ++j) {
                V[i][ch*16 + h*8 + 2*j]     = __uint_as_float(u[j] << 16);
                V[i][ch*16 + h*8 + 2*j + 1] = __uint_as_float(u[j] & 0xFFFF0000u);
            }
        }
    }
    __syncthreads();

    // L4: h4[i][c] = b4[c] + sum_k V[i][k] W4[k][c]; thread = (c, 8 clusters).
    {
        const int c  = t & 127;
        const int ih = t >> 7;
        float acc[8];
        #pragma unroll
        for (int i = 0; i < 8; ++i) acc[i] = b4[c];
        for (int k4 = 0; k4 < 64; ++k4) {
            const float w0 = W4[(4*k4+0)*128 + c];
            const float w1 = W4[(4*k4+1)*128 + c];
            const float w2 = W4[(4*k4+2)*128 + c];
            const float w3 = W4[(4*k4+3)*128 + c];
            #pragma unroll
            for (int i = 0; i < 8; ++i) {
                const float4 vv = *(const float4*)&V[ih*8 + i][4*k4];
                acc[i] = fmaf(vv.x, w0, fmaf(vv.y, w1,
                         fmaf(vv.z, w2, fmaf(vv.w, w3, acc[i]))));
            }
        }
        #pragma unroll
        for (int i = 0; i < 8; ++i) H4[ih*8 + i][c] = acc[i];
    }
    __syncthreads();

    // L5: h5[i][c] = b5[c] + sum_k H4[i][k] W5[k][c]; thread = (c, 4 clusters).
    {
        const int c  = t & 63;
        const int iq = t >> 6;
        float acc[4];
        #pragma unroll
        for (int i = 0; i < 4; ++i) acc[i] = b5[c];
        for (int k4 = 0; k4 < 32; ++k4) {
            const float w0 = W5[(4*k4+0)*64 + c];
            const float w1 = W5[(4*k4+1)*64 + c];
            const float w2 = W5[(4*k4+2)*64 + c];
            const float w3 = W5[(4*k4+3)*64 + c];
            #pragma unroll
            for (int i = 0; i < 4; ++i) {
                const float4 vv = *(const float4*)&H4[iq*4 + i][4*k4];
                acc[i] = fmaf(vv.x, w0, fmaf(vv.y, w1,
                         fmaf(vv.z, w2, fmaf(vv.w, w3, acc[i]))));
            }
        }
        #pragma unroll
        for (int i = 0; i < 4; ++i) H5[iq*4 + i][c] = acc[i];
    }
    __syncthreads();

    // Heads: wave wv handles clusters 4wv..4wv+3. attention = softplus(h5.Wa+ba);
    // orientation = atan2(o1,o0) (normalization is scale-invariant -> skipped).
    {
        const int wv = t >> 6, l = t & 63;
        const float wa  = Wa[l];
        const float wo0 = Wo[2*l + 0];
        const float wo1 = Wo[2*l + 1];
        #pragma unroll
        for (int i = 0; i < 4; ++i) {
            const float hv = H5[4*wv + i][l];
            float va = hv * wa;
            float v0 = hv * wo0;
            float v1 = hv * wo1;
            #pragma unroll
            for (int off = 32; off > 0; off >>= 1) {
                va += __shfl_down(va, off);
                v0 += __shfl_down(v0, off);
                v1 += __shfl_down(v1, off);
            }
            if (l == 0) {
                const int cg = cl0 + 4*wv + i;
                const float a = va + ba[0];
                out[OUT_ATT + cg] = fmaxf(a, 0.f) + log1pf(expf(-fabsf(a)));
                out[OUT_ORI + cg] = atan2f(v1 + bo[1], v0 + bo[0]);
            }
        }
    }
}

extern "C" void kernel_launch(void* const* d_in, const int* in_sizes, int n_in,
                              void* d_out, int out_size, void* d_ws, size_t ws_size,
                              hipStream_t stream) {
    const float* xyz = (const float*)d_in[0];
    const float* W1  = (const float*)d_in[1];
    const float* b1  = (const float*)d_in[2];
    const float* W2  = (const float*)d_in[3];
    const float* b2  = (const float*)d_in[4];
    const float* W3  = (const float*)d_in[5];
    const float* b3  = (const float*)d_in[6];
    const float* W4  = (const float*)d_in[7];
    const float* b4  = (const float*)d_in[8];
    const float* W5  = (const float*)d_in[9];
    const float* b5  = (const float*)d_in[10];
    const float* Wa  = (const float*)d_in[11];
    const float* ba  = (const float*)d_in[12];
    const float* Wo  = (const float*)d_in[13];
    const float* bo  = (const float*)d_in[14];

    unsigned short* ws = (unsigned short*)d_ws;
    unsigned long long* msk = (unsigned long long*)((char*)d_ws + WS_MASK_BYTES);
    float* gws = (float*)((char*)d_ws + WS_G_BYTES);

    pack_weights<<<dim3(20), dim3(256), 0, stream>>>(W2, W3, ws);
    feat3d_mask<<<dim3(512), dim3(256), 0, stream>>>(xyz, msk);
    feat3d_select<<<dim3(NCLUST/4), dim3(256), 0, stream>>>(
        xyz, msk, gws, (float*)d_out);
    feat3d_mlp<<<dim3(NCLUST), dim3(256), 0, stream>>>(
        gws, W1, b1, b2, b3, ws, ws + WS_V);
    feat3d_tail<<<dim3(NCLUST/16), dim3(256), 0, stream>>>(
        ws + WS_V, W4, b4, W5, b5, Wa, ba, Wo, bo, (float*)d_out);
}